// Round 2
// baseline (277.118 us; speedup 1.0000x reference)
//
#include <hip/hip_runtime.h>
#include <math.h>

#define NLB 96          // L*B = 3*32
#define CC  256
#define PP  49
#define QQ  961
#define TEMP_INV 40.0f  // 1/0.025
#define BN_EPS 1e-5f

#define N1 (NLB*CC*PP)  // 1,204,224
#define N2 (NLB*CC*QQ)  // 23,617,536

// -------- Kernel 1: A[lb,p,q] = normalized correlation, fused norms --------
// grid (4, 96), block 256. Each block: one (lb, 256-wide q chunk).
// f1 loads are wave-uniform -> scalar loads; f2 streamed coalesced.
__global__ __launch_bounds__(256) void corr_kernel(
    const float* __restrict__ zf, const float* __restrict__ xf,
    float* __restrict__ A_all)
{
    const int lb    = blockIdx.y;
    const int chunk = blockIdx.x;
    const int q     = chunk * 256 + threadIdx.x;
    const bool active = (q < QQ);
    const int qc    = active ? q : (QQ - 1);

    const float* __restrict__ f1 = zf + (size_t)lb * CC * PP;
    const float* __restrict__ f2 = xf + (size_t)lb * CC * QQ;

    __shared__ float inv1[PP];
    if (threadIdx.x < PP) {
        const int p = threadIdx.x;
        float ss = 0.f;
        for (int c = 0; c < CC; ++c) { float v = f1[c * PP + p]; ss = fmaf(v, v, ss); }
        inv1[p] = 1.0f / fmaxf(sqrtf(ss), 1e-12f);
    }
    __syncthreads();

    float acc[PP];
#pragma unroll
    for (int p = 0; p < PP; ++p) acc[p] = 0.f;
    float ssq2 = 0.f;

    for (int c = 0; c < CC; ++c) {
        const float v = f2[c * QQ + qc];
        ssq2 = fmaf(v, v, ssq2);
#pragma unroll
        for (int p = 0; p < PP; ++p) acc[p] = fmaf(f1[c * PP + p], v, acc[p]);
    }

    const float inv2 = 1.0f / fmaxf(sqrtf(ssq2), 1e-12f);
    if (active) {
        float* __restrict__ Arow = A_all + (size_t)lb * PP * QQ;
#pragma unroll
        for (int p = 0; p < PP; ++p)
            Arow[p * QQ + q] = acc[p] * inv1[p] * inv2;
    }
}

// -------- Kernel 2: per-(l,b) attention: means -> MLPs -> s -> softmax ------
// grid 96, block 256 (4 waves).
__global__ __launch_bounds__(256) void attn_kernel(
    const float* __restrict__ A_all,
    const float* __restrict__ W1, const float* __restrict__ b1,
    const float* __restrict__ g1, const float* __restrict__ bb1,
    const float* __restrict__ rm1, const float* __restrict__ rv1,
    const float* __restrict__ W2, const float* __restrict__ b2,
    const float* __restrict__ W3, const float* __restrict__ b3,
    const float* __restrict__ g3, const float* __restrict__ bb3,
    const float* __restrict__ rm3, const float* __restrict__ rv3,
    const float* __restrict__ W4, const float* __restrict__ b4,
    float* __restrict__ att1_ws, float* __restrict__ att2_ws)
{
    const int lb = blockIdx.x;
    const float* __restrict__ A = A_all + (size_t)lb * PP * QQ;
    const int tid  = threadIdx.x;
    const int lane = tid & 63;
    const int wave = tid >> 6;

    __shared__ float mcol[QQ];
    __shared__ float mrow[PP];
    __shared__ float ta[32], tb[8];
    __shared__ float t2a[QQ], t2b[PP];
    __shared__ float s2s[QQ];
    __shared__ float s1s[PP];
    __shared__ float red[8];

    // 1. column means (over p)
    for (int q = tid; q < QQ; q += 256) {
        float s = 0.f;
#pragma unroll
        for (int p = 0; p < PP; ++p) s += A[p * QQ + q];
        mcol[q] = s * (1.0f / PP);
    }
    // 2. row means (over q), one wave per p round-robin
    for (int p = wave; p < PP; p += 4) {
        float s = 0.f;
        for (int q = lane; q < QQ; q += 64) s += A[p * QQ + q];
        for (int off = 32; off > 0; off >>= 1) s += __shfl_xor(s, off, 64);
        if (lane == 0) mrow[p] = s * (1.0f / QQ);
    }
    __syncthreads();

    // 3. hidden layers (BN inference + relu)
    if (tid < 31) {
        const int k = tid;
        float s = 0.f;
        for (int q = 0; q < QQ; ++q) s = fmaf(mcol[q], W1[k * QQ + q], s);
        s += b1[k];
        s = (s - rm1[k]) * rsqrtf(rv1[k] + BN_EPS) * g1[k] + bb1[k];
        ta[k] = fmaxf(s, 0.f);
    } else if (tid >= 64 && tid < 64 + 7) {
        const int k = tid - 64;
        float s = 0.f;
#pragma unroll
        for (int p = 0; p < PP; ++p) s = fmaf(mrow[p], W3[k * PP + p], s);
        s += b3[k];
        s = (s - rm3[k]) * rsqrtf(rv3[k] + BN_EPS) * g3[k] + bb3[k];
        tb[k] = fmaxf(s, 0.f);
    }
    __syncthreads();

    // 4. back-projection t2a[q], t2b[p]
    for (int q = tid; q < QQ; q += 256) {
        float s = b2[q];
#pragma unroll
        for (int k = 0; k < 31; ++k) s = fmaf(ta[k], W2[q * 31 + k], s);
        t2a[q] = s;
    }
    if (tid < PP) {
        float s = b4[tid];
#pragma unroll
        for (int k = 0; k < 7; ++k) s = fmaf(tb[k], W4[tid * 7 + k], s);
        t2b[tid] = s;
    }
    __syncthreads();

    // 5. s2[q] = mean_p A*t2b; s1[p] = mean_q A*t2a  (pre-scaled by 1/TEMP)
    for (int q = tid; q < QQ; q += 256) {
        float s = 0.f;
#pragma unroll
        for (int p = 0; p < PP; ++p) s = fmaf(A[p * QQ + q], t2b[p], s);
        s2s[q] = s * (1.0f / PP) * TEMP_INV;
    }
    for (int p = wave; p < PP; p += 4) {
        float s = 0.f;
        for (int q = lane; q < QQ; q += 64) s = fmaf(A[p * QQ + q], t2a[q], s);
        for (int off = 32; off > 0; off >>= 1) s += __shfl_xor(s, off, 64);
        if (lane == 0) s1s[p] = s * (1.0f / QQ) * TEMP_INV;
    }
    __syncthreads();

    // 6. softmax over P=49 (wave 0) -> att1
    if (wave == 0) {
        const float v = (lane < PP) ? s1s[lane] : -3.4e38f;
        float m = v;
        for (int off = 32; off > 0; off >>= 1) m = fmaxf(m, __shfl_xor(m, off, 64));
        const float e = (lane < PP) ? expf(v - m) : 0.f;
        float sum = e;
        for (int off = 32; off > 0; off >>= 1) sum += __shfl_xor(sum, off, 64);
        if (lane < PP) att1_ws[lb * PP + lane] = e / sum + 1.0f;
    }

    // 7. softmax over Q=961 (block-wide) -> att2
    float lm = -3.4e38f;
    for (int q = tid; q < QQ; q += 256) lm = fmaxf(lm, s2s[q]);
    for (int off = 32; off > 0; off >>= 1) lm = fmaxf(lm, __shfl_xor(lm, off, 64));
    if (lane == 0) red[wave] = lm;
    __syncthreads();
    const float gm = fmaxf(fmaxf(red[0], red[1]), fmaxf(red[2], red[3]));
    float ls = 0.f;
    for (int q = tid; q < QQ; q += 256) ls += expf(s2s[q] - gm);
    for (int off = 32; off > 0; off >>= 1) ls += __shfl_xor(ls, off, 64);
    if (lane == 0) red[4 + wave] = ls;
    __syncthreads();
    const float gsum = red[4] + red[5] + red[6] + red[7];
    const float rinv = 1.0f / gsum;
    for (int q = tid; q < QQ; q += 256)
        att2_ws[lb * QQ + q] = expf(s2s[q] - gm) * rinv + 1.0f;
}

// -------- Kernel 3/4: out = in * att[lb, inner], float4-vectorized ----------
template <int INNER>
__global__ __launch_bounds__(256) void scale_kernel(
    const float* __restrict__ in, const float* __restrict__ att,
    float* __restrict__ out, int n4)
{
    const int i = blockIdx.x * 256 + threadIdx.x;
    if (i >= n4) return;
    const float4 v = reinterpret_cast<const float4*>(in)[i];
    const float* vv = reinterpret_cast<const float*>(&v);
    float4 o;
    float* ov = reinterpret_cast<float*>(&o);
    const int g = i * 4;
#pragma unroll
    for (int j = 0; j < 4; ++j) {
        const int gg = g + j;
        const int lb = gg / (CC * INNER);
        const int x  = gg % INNER;
        ov[j] = vv[j] * att[lb * INNER + x];
    }
    reinterpret_cast<float4*>(out)[i] = o;
}

extern "C" void kernel_launch(void* const* d_in, const int* in_sizes, int n_in,
                              void* d_out, int out_size, void* d_ws, size_t ws_size,
                              hipStream_t stream)
{
    const float* zf  = (const float*)d_in[0];
    const float* xf  = (const float*)d_in[1];
    const float* W1  = (const float*)d_in[2];
    const float* b1  = (const float*)d_in[3];
    const float* g1  = (const float*)d_in[4];
    const float* bb1 = (const float*)d_in[5];
    const float* rm1 = (const float*)d_in[6];
    const float* rv1 = (const float*)d_in[7];
    const float* W2  = (const float*)d_in[8];
    const float* b2  = (const float*)d_in[9];
    const float* W3  = (const float*)d_in[10];
    const float* b3  = (const float*)d_in[11];
    const float* g3  = (const float*)d_in[12];
    const float* bb3 = (const float*)d_in[13];
    const float* rm3 = (const float*)d_in[14];
    const float* rv3 = (const float*)d_in[15];
    const float* W4  = (const float*)d_in[16];
    const float* b4  = (const float*)d_in[17];

    float* ws   = (float*)d_ws;
    float* A    = ws;                               // 96*49*961
    float* att1 = A + (size_t)NLB * PP * QQ;        // 96*49
    float* att2 = att1 + (size_t)NLB * PP;          // 96*961

    float* out1 = (float*)d_out;
    float* out2 = out1 + N1;

    dim3 gcorr(4, NLB);
    corr_kernel<<<gcorr, 256, 0, stream>>>(zf, xf, A);

    attn_kernel<<<NLB, 256, 0, stream>>>(A,
        W1, b1, g1, bb1, rm1, rv1, W2, b2,
        W3, b3, g3, bb3, rm3, rv3, W4, b4,
        att1, att2);

    const int n4_1 = N1 / 4;
    const int n4_2 = N2 / 4;
    scale_kernel<PP><<<(n4_1 + 255) / 256, 256, 0, stream>>>(zf, att1, out1, n4_1);
    scale_kernel<QQ><<<(n4_2 + 255) / 256, 256, 0, stream>>>(xf, att2, out2, n4_2);
}

// Round 4
// 162.358 us; speedup vs baseline: 1.7068x; 1.7068x over previous
//
#include <hip/hip_runtime.h>
#include <math.h>

#define NLB 96          // L*B = 3*32
#define CC  256
#define PP  49
#define QQ  961
#define TEMP_INV 40.0f  // 1/0.025
#define BN_EPS 1e-5f

#define N1 (NLB*CC*PP)  // 1,204,224
#define N2 (NLB*CC*QQ)  // 23,617,536

typedef __attribute__((ext_vector_type(8))) short bf16x8;
typedef __attribute__((ext_vector_type(4))) float f32x4;

__device__ inline unsigned short f2bf(float x) {  // RNE float->bf16
    unsigned int u = __float_as_uint(x);
    unsigned int r = (u + 0x7fffu + ((u >> 16) & 1u)) >> 16;
    return (unsigned short)r;
}

// ---------------- Kernel 1: MFMA correlation + fused norms + means ----------
// grid (4 n-groups, 96 lb), 256 threads (4 waves).
// C[49x961] = f1^T(49x256) * f2(256x961), scaled by inv1[p]*inv2[q].
// Each block: one lb, one 256-wide q group. f1 staged to LDS as bf16 [p][k];
// f2 staged per 64-k chunk as bf16 [q][k]. mcol written directly (complete
// per q here); mrow accumulated via atomicAdd (ws pre-zeroed).
__global__ __launch_bounds__(256) void corr_mfma(
    const float* __restrict__ zf, const float* __restrict__ xf,
    float* __restrict__ A_all, float* __restrict__ mcol_ws,
    float* __restrict__ mrow_ws)
{
    const int ng = blockIdx.x;           // 0..3, q range [ng*256, ng*256+256)
    const int lb = blockIdx.y;
    const int tid  = threadIdx.x;
    const int lane = tid & 63;
    const int wave = tid >> 6;
    const int g4   = lane >> 4;          // 0..3
    const int l15  = lane & 15;

    const float* __restrict__ f1 = zf + (size_t)lb * CC * PP;   // [c][p]
    const float* __restrict__ f2 = xf + (size_t)lb * CC * QQ;   // [c][q]
    float* __restrict__ Aout = A_all + (size_t)lb * PP * QQ;

    // LDS: f1 as bf16 [64 rows p][264 k-slots] (row 528B, 16B-mult, bank-friendly)
    __shared__ __align__(16) unsigned short f1L[64 * 264];
    __shared__ __align__(16) unsigned short Bb[256 * 72];   // f2 chunk [q][72] (144B rows)
    __shared__ float inv1L[64];
    __shared__ float inv2L[256];

    // ---- stage f1 -> LDS (transpose to [p][k]), pad rows 49..63 with zeros
    for (int i = tid; i < CC * PP; i += 256) {
        const int c = i / PP;
        const int p = i - c * PP;
        f1L[p * 264 + c] = f2bf(f1[i]);
    }
    for (int i = tid; i < 15 * 256; i += 256) {
        const int p = 49 + (i >> 8);
        const int k = i & 255;
        f1L[p * 264 + k] = 0;
    }
    // ---- inv1[p] from fp32 f1 (4 lanes per p)
    {
        const int p = tid >> 2, sub = tid & 3;
        float ss = 0.f;
        if (p < PP)
            for (int c = sub; c < CC; c += 4) { float v = f1[c * PP + p]; ss = fmaf(v, v, ss); }
        ss += __shfl_xor(ss, 1, 64);
        ss += __shfl_xor(ss, 2, 64);
        if (sub == 0) inv1L[p] = (p < PP) ? 1.0f / fmaxf(sqrtf(ss), 1e-12f) : 0.f;
    }
    __syncthreads();

    const int ntCount = (ng < 3) ? 16 : 13;      // n-tiles of 16 q in this group
    const int q = ng * 256 + tid;                // this thread's staging column
    const bool qv = (q < QQ);

    f32x4 acc[4][4];
#pragma unroll
    for (int i = 0; i < 4; ++i)
#pragma unroll
        for (int mt = 0; mt < 4; ++mt) acc[i][mt] = (f32x4)0.f;

    float ss2 = 0.f;   // sum of squares of this q column (fp32)

    for (int kc = 0; kc < 4; ++kc) {             // k chunks of 64
        // ---- stage f2 chunk (bf16 pairs), accumulate column sumsq
#pragma unroll 8
        for (int cc = 0; cc < 64; cc += 2) {
            const int c = kc * 64 + cc;
            const float v0 = qv ? f2[(size_t)c * QQ + q] : 0.f;
            const float v1 = qv ? f2[(size_t)(c + 1) * QQ + q] : 0.f;
            ss2 = fmaf(v0, v0, fmaf(v1, v1, ss2));
            const unsigned int pk = (unsigned int)f2bf(v0) | ((unsigned int)f2bf(v1) << 16);
            *(unsigned int*)&Bb[tid * 72 + cc] = pk;
        }
        __syncthreads();

        // ---- A fragments for this chunk (shared across n-tiles)
        bf16x8 af[4][2];
#pragma unroll
        for (int mt = 0; mt < 4; ++mt)
#pragma unroll
            for (int ks = 0; ks < 2; ++ks)
                af[mt][ks] = *(const bf16x8*)&f1L[(mt * 16 + l15) * 264 + kc * 64 + ks * 32 + 8 * g4];

        // ---- MFMA: wave handles n-tiles wave, wave+4, wave+8, wave+12
#pragma unroll
        for (int i = 0; i < 4; ++i) {
            const int nt = wave + 4 * i;
            if (nt < ntCount) {
                const int row = nt * 16 + l15;
#pragma unroll
                for (int ks = 0; ks < 2; ++ks) {
                    const bf16x8 bfr = *(const bf16x8*)&Bb[row * 72 + ks * 32 + 8 * g4];
#pragma unroll
                    for (int mt = 0; mt < 4; ++mt)
                        acc[i][mt] = __builtin_amdgcn_mfma_f32_16x16x32_bf16(af[mt][ks], bfr, acc[i][mt], 0, 0, 0);
                }
            }
        }
        __syncthreads();
    }

    inv2L[tid] = qv ? 1.0f / fmaxf(sqrtf(ss2), 1e-12f) : 0.f;
    __syncthreads();

    // ---- epilogue: scale, store A, col-sums (mcol), row-sums (mrow atomics)
#pragma unroll
    for (int i = 0; i < 4; ++i) {
        const int nt = wave + 4 * i;
        if (nt >= ntCount) continue;
        const int qg = ng * 256 + nt * 16 + l15;
        const bool qvv = (qg < QQ);
        const float iv2 = inv2L[nt * 16 + l15];
        float vv[16];
        float cs = 0.f;
#pragma unroll
        for (int mt = 0; mt < 4; ++mt)
#pragma unroll
            for (int r = 0; r < 4; ++r) {
                const int p = mt * 16 + g4 * 4 + r;
                const float v = acc[i][mt][r] * inv1L[p] * iv2;
                vv[mt * 4 + r] = v;
                cs += v;
                if (p < PP && qvv) Aout[(size_t)p * QQ + qg] = v;
            }
        // column sum over p: reduce across the 4 row-groups (lane>>4)
        cs += __shfl_xor(cs, 16, 64);
        cs += __shfl_xor(cs, 32, 64);
        if ((lane < 16) && qvv) mcol_ws[lb * QQ + qg] = cs;
        // row sums over the 16 q of this tile -> atomic into mrow
#pragma unroll
        for (int mt = 0; mt < 4; ++mt)
#pragma unroll
            for (int r = 0; r < 4; ++r) {
                const int p = mt * 16 + g4 * 4 + r;
                float s = vv[mt * 4 + r];
                s += __shfl_xor(s, 1, 64);
                s += __shfl_xor(s, 2, 64);
                s += __shfl_xor(s, 4, 64);
                s += __shfl_xor(s, 8, 64);
                if (((lane & 15) == 0) && p < PP) atomicAdd(&mrow_ws[lb * PP + p], s);
            }
    }
}

// ---------------- Kernel 2: attention MLPs + softmaxes ---------------------
// grid 96, block 512 (8 waves). All GEMVs lane-parallel with shuffle reduce.
__global__ __launch_bounds__(512) void attn_kernel(
    const float* __restrict__ A_all,
    const float* __restrict__ mcol_ws, const float* __restrict__ mrow_ws,
    const float* __restrict__ W1, const float* __restrict__ b1,
    const float* __restrict__ g1, const float* __restrict__ bb1,
    const float* __restrict__ rm1, const float* __restrict__ rv1,
    const float* __restrict__ W2, const float* __restrict__ b2,
    const float* __restrict__ W3, const float* __restrict__ b3,
    const float* __restrict__ g3, const float* __restrict__ bb3,
    const float* __restrict__ rm3, const float* __restrict__ rv3,
    const float* __restrict__ W4, const float* __restrict__ b4,
    float* __restrict__ att1_ws, float* __restrict__ att2_ws)
{
    const int lb = blockIdx.x;
    const float* __restrict__ A = A_all + (size_t)lb * PP * QQ;
    const int tid  = threadIdx.x;
    const int lane = tid & 63;
    const int wv   = tid >> 6;

    __shared__ float mcolL[QQ];
    __shared__ float mrowL[PP];
    __shared__ float taL[31], tbL[7];
    __shared__ float t2aL[QQ], t2bL[PP];
    __shared__ float s2sL[QQ];
    __shared__ float s1L[PP];
    __shared__ float redM[8], redS[8];

    for (int q = tid; q < QQ; q += 512) mcolL[q] = mcol_ws[lb * QQ + q] * (1.0f / PP);
    if (tid < PP) mrowL[tid] = mrow_ws[lb * PP + tid] * (1.0f / QQ);
    __syncthreads();

    // GEMV1: ta[k] = BNrelu(W1[k,:]@mcol + b1[k]), 16 lanes per k
    if (tid < 31 * 16) {
        const int k = tid >> 4, sub = tid & 15;
        float s = 0.f;
        for (int q = sub; q < QQ; q += 16) s = fmaf(mcolL[q], W1[k * QQ + q], s);
        s += __shfl_xor(s, 1, 64); s += __shfl_xor(s, 2, 64);
        s += __shfl_xor(s, 4, 64); s += __shfl_xor(s, 8, 64);
        if (sub == 0) {
            float t = s + b1[k];
            t = (t - rm1[k]) * rsqrtf(rv1[k] + BN_EPS) * g1[k] + bb1[k];
            taL[k] = fmaxf(t, 0.f);
        }
    }
    // GEMV3: tb[k] = BNrelu(W3[k,:]@mrow + b3[k]), 8 lanes per k
    if (tid < 7 * 8) {
        const int k = tid >> 3, sub = tid & 7;
        float s = 0.f;
        for (int p = sub; p < PP; p += 8) s = fmaf(mrowL[p], W3[k * PP + p], s);
        s += __shfl_xor(s, 1, 64); s += __shfl_xor(s, 2, 64); s += __shfl_xor(s, 4, 64);
        if (sub == 0) {
            float t = s + b3[k];
            t = (t - rm3[k]) * rsqrtf(rv3[k] + BN_EPS) * g3[k] + bb3[k];
            tbL[k] = fmaxf(t, 0.f);
        }
    }
    __syncthreads();

    // back-projections
    for (int q = tid; q < QQ; q += 512) {
        float s = b2[q];
#pragma unroll
        for (int k = 0; k < 31; ++k) s = fmaf(taL[k], W2[q * 31 + k], s);
        t2aL[q] = s;
    }
    if (tid < PP) {
        float s = b4[tid];
#pragma unroll
        for (int k = 0; k < 7; ++k) s = fmaf(tbL[k], W4[tid * 7 + k], s);
        t2bL[tid] = s;
    }
    __syncthreads();

    // s2[q] = mean_p A[p][q]*t2b[p]; s1[p] = mean_q A[p][q]*t2a[q]
    for (int q = tid; q < QQ; q += 512) {
        float s = 0.f;
#pragma unroll
        for (int p = 0; p < PP; ++p) s = fmaf(A[(size_t)p * QQ + q], t2bL[p], s);
        s2sL[q] = s * (1.0f / PP) * TEMP_INV;
    }
    for (int p = wv; p < PP; p += 8) {
        float s = 0.f;
        for (int q = lane; q < QQ; q += 64) s = fmaf(A[(size_t)p * QQ + q], t2aL[q], s);
        for (int off = 32; off > 0; off >>= 1) s += __shfl_xor(s, off, 64);
        if (lane == 0) s1L[p] = s * (1.0f / QQ) * TEMP_INV;
    }
    __syncthreads();

    // softmax over P (wave 0)
    if (wv == 0) {
        const float v = (lane < PP) ? s1L[lane] : -3.4e38f;
        float m = v;
        for (int off = 32; off > 0; off >>= 1) m = fmaxf(m, __shfl_xor(m, off, 64));
        const float e = (lane < PP) ? expf(v - m) : 0.f;
        float sum = e;
        for (int off = 32; off > 0; off >>= 1) sum += __shfl_xor(sum, off, 64);
        if (lane < PP) att1_ws[lb * PP + lane] = e / sum + 1.0f;
    }

    // softmax over Q (block-wide, 8 waves)
    float lm = -3.4e38f;
    for (int q = tid; q < QQ; q += 512) lm = fmaxf(lm, s2sL[q]);
    for (int off = 32; off > 0; off >>= 1) lm = fmaxf(lm, __shfl_xor(lm, off, 64));
    if (lane == 0) redM[wv] = lm;
    __syncthreads();
    float gm = redM[0];
#pragma unroll
    for (int i = 1; i < 8; ++i) gm = fmaxf(gm, redM[i]);
    float ls = 0.f;
    for (int q = tid; q < QQ; q += 512) ls += expf(s2sL[q] - gm);
    for (int off = 32; off > 0; off >>= 1) ls += __shfl_xor(ls, off, 64);
    if (lane == 0) redS[wv] = ls;
    __syncthreads();
    float tot = 0.f;
#pragma unroll
    for (int i = 0; i < 8; ++i) tot += redS[i];
    const float rinv = 1.0f / tot;
    for (int q = tid; q < QQ; q += 512)
        att2_ws[lb * QQ + q] = expf(s2sL[q] - gm) * rinv + 1.0f;
}

// -------- Kernel 3/4: out = in * att[lb, inner], float4-vectorized ----------
template <int INNER>
__global__ __launch_bounds__(256) void scale_kernel(
    const float* __restrict__ in, const float* __restrict__ att,
    float* __restrict__ out, int n4)
{
    const int i = blockIdx.x * 256 + threadIdx.x;
    if (i >= n4) return;
    const float4 v = reinterpret_cast<const float4*>(in)[i];
    const float* vv = reinterpret_cast<const float*>(&v);
    float4 o;
    float* ov = reinterpret_cast<float*>(&o);
    const int g = i * 4;
#pragma unroll
    for (int j = 0; j < 4; ++j) {
        const int gg = g + j;
        const int lb = gg / (CC * INNER);
        const int x  = gg % INNER;
        ov[j] = vv[j] * att[lb * INNER + x];
    }
    reinterpret_cast<float4*>(out)[i] = o;
}

extern "C" void kernel_launch(void* const* d_in, const int* in_sizes, int n_in,
                              void* d_out, int out_size, void* d_ws, size_t ws_size,
                              hipStream_t stream)
{
    const float* zf  = (const float*)d_in[0];
    const float* xf  = (const float*)d_in[1];
    const float* W1  = (const float*)d_in[2];
    const float* b1  = (const float*)d_in[3];
    const float* g1  = (const float*)d_in[4];
    const float* bb1 = (const float*)d_in[5];
    const float* rm1 = (const float*)d_in[6];
    const float* rv1 = (const float*)d_in[7];
    const float* W2  = (const float*)d_in[8];
    const float* b2  = (const float*)d_in[9];
    const float* W3  = (const float*)d_in[10];
    const float* b3  = (const float*)d_in[11];
    const float* g3  = (const float*)d_in[12];
    const float* bb3 = (const float*)d_in[13];
    const float* rm3 = (const float*)d_in[14];
    const float* rv3 = (const float*)d_in[15];
    const float* W4  = (const float*)d_in[16];
    const float* b4  = (const float*)d_in[17];

    float* ws   = (float*)d_ws;
    float* A    = ws;                               // 96*49*961
    float* att1 = A + (size_t)NLB * PP * QQ;        // 96*49
    float* att2 = att1 + (size_t)NLB * PP;          // 96*961
    float* mcol = att2 + (size_t)NLB * QQ;          // 96*961
    float* mrow = mcol + (size_t)NLB * QQ;          // 96*49

    float* out1 = (float*)d_out;
    float* out2 = out1 + N1;

    hipMemsetAsync(mrow, 0, (size_t)NLB * PP * sizeof(float), stream);

    dim3 gcorr(4, NLB);
    corr_mfma<<<gcorr, 256, 0, stream>>>(zf, xf, A, mcol, mrow);

    attn_kernel<<<NLB, 512, 0, stream>>>(A, mcol, mrow,
        W1, b1, g1, bb1, rm1, rv1, W2, b2,
        W3, b3, g3, bb3, rm3, rv3, W4, b4,
        att1, att2);

    const int n4_1 = N1 / 4;
    const int n4_2 = N2 / 4;
    scale_kernel<PP><<<(n4_1 + 255) / 256, 256, 0, stream>>>(zf, att1, out1, n4_1);
    scale_kernel<QQ><<<(n4_2 + 255) / 256, 256, 0, stream>>>(xf, att2, out2, n4_2);
}